// Round 1
// baseline (192.673 us; speedup 1.0000x reference)
//
#include <hip/hip_runtime.h>

#define HW_   5776   // 76*76
#define W_    76
#define NC_   80     // classes
#define NA_   3      // anchors
#define NB_   16     // batch
#define NCH_  85     // 5 + NC_

__device__ __forceinline__ float sigmoidf_(float x) {
    return 1.0f / (1.0f + __expf(-x));
}

__global__ __launch_bounds__(256) void yolo_kernel(const float* __restrict__ in,
                                                   float* __restrict__ out) {
    const int p = blockIdx.x * 256 + threadIdx.x;   // position in 76x76 plane
    if (p >= HW_) return;
    const int a = blockIdx.y;
    const int b = blockIdx.z;

    // anchors / stride folded: [12,19,40]/8 and [16,36,28]/8
    const float aw3[3] = {1.5f, 2.375f, 5.0f};
    const float ah3[3] = {2.0f, 4.5f, 3.5f};
    const float invW = 1.0f / 76.0f;

    // load all 85 channels for this (b, a, p); channel stride = HW_
    const float* src = in + (size_t)(b * NA_ + a) * NCH_ * HW_ + p;
    float v[NCH_];
#pragma unroll
    for (int ch = 0; ch < NCH_; ++ch) {
        v[ch] = src[(size_t)ch * HW_];
    }

    const int x = p % W_;
    const int y = p / W_;

    const float bx  = (sigmoidf_(v[0]) + (float)x) * invW;
    const float by  = (sigmoidf_(v[1]) + (float)y) * invW;
    const float bw  = __expf(v[2]) * (aw3[a] * invW);
    const float bh  = __expf(v[3]) * (ah3[a] * invW);
    const float det = sigmoidf_(v[4]);

    // softmax over classes (max-stabilized, in registers)
    float m = v[5];
#pragma unroll
    for (int c = 1; c < NC_; ++c) m = fmaxf(m, v[5 + c]);
    float s = 0.0f;
#pragma unroll
    for (int c = 0; c < NC_; ++c) {
        v[5 + c] = __expf(v[5 + c] - m);
        s += v[5 + c];
    }
    const float scale = det / s;

    // ---- outputs ----
    // boxes: [B][A*HW][4], then confs: [B][A*HW][NC]
    const size_t idx = (size_t)a * HW_ + (size_t)p;          // within-batch row
    float4* boxout = (float4*)out + (size_t)b * (NA_ * HW_) + idx;
    *boxout = make_float4(bx, by, bw, bh);

    float* conf = out + (size_t)NB_ * NA_ * HW_ * 4
                      + ((size_t)b * (NA_ * HW_) + idx) * NC_;
#pragma unroll
    for (int c = 0; c < NC_; c += 4) {
        float4 val = make_float4(v[5 + c]     * scale,
                                 v[5 + c + 1] * scale,
                                 v[5 + c + 2] * scale,
                                 v[5 + c + 3] * scale);
        *(float4*)(conf + c) = val;
    }
}

extern "C" void kernel_launch(void* const* d_in, const int* in_sizes, int n_in,
                              void* d_out, int out_size, void* d_ws, size_t ws_size,
                              hipStream_t stream) {
    const float* in = (const float*)d_in[0];
    float* out = (float*)d_out;
    dim3 grid((HW_ + 255) / 256, NA_, NB_);
    yolo_kernel<<<grid, 256, 0, stream>>>(in, out);
}

// Round 2
// 184.695 us; speedup vs baseline: 1.0432x; 1.0432x over previous
//
#include <hip/hip_runtime.h>

#define HW_   5776   // 76*76
#define W_    76
#define NC_   80     // classes
#define NA_   3      // anchors
#define NB_   16     // batch
#define NCH_  85     // 5 + NC_
#define NPOS  (NB_ * NA_ * HW_)   // 277248 total positions

__device__ __forceinline__ float sigmoidf_(float x) {
    return 1.0f / (1.0f + __expf(-x));
}

// Two lanes per position: lane i (half 0) handles box + classes 0..39,
// lane i^32 (half 1) handles classes 40..79. Softmax max/sum combined via
// __shfl_xor(.,32). Box channels loaded by both halves (same addresses in
// the same instruction -> merged by the coalescer, no extra traffic).
__global__ __launch_bounds__(256) void yolo_kernel(const float* __restrict__ in,
                                                   float* __restrict__ out) {
    const int tid  = threadIdx.x;
    const int lane = tid & 63;
    const int wv   = tid >> 6;            // wave within block (0..3)
    const int half = lane >> 5;           // 0 or 1
    // 128 positions per block; grid sized so no bounds check needed
    const int P = blockIdx.x * 128 + wv * 32 + (lane & 31);

    const int slab = P / HW_;             // = b*3 + a   (0..47)
    const int p    = P - slab * HW_;      // position in 76x76 plane
    const int a    = slab % NA_;

    const float aw3[3] = {1.5f, 2.375f, 5.0f};   // [12,19,40]/8
    const float ah3[3] = {2.0f, 4.5f, 3.5f};     // [16,36,28]/8
    const float invW = 1.0f / 76.0f;

    const float* src = in + (size_t)slab * (NCH_ * HW_) + p;

    // box channels 0..4 (redundant across halves, coalescer-merged)
    const float b0 = src[0 * (size_t)HW_];
    const float b1 = src[1 * (size_t)HW_];
    const float b2 = src[2 * (size_t)HW_];
    const float b3 = src[3 * (size_t)HW_];
    const float b4 = src[4 * (size_t)HW_];

    // this half's 40 class channels
    const float* csrc = src + (size_t)(5 + half * 40) * HW_;
    float v[40];
#pragma unroll
    for (int c = 0; c < 40; ++c) v[c] = csrc[(size_t)c * HW_];

    const int x = p % W_;
    const int y = p / W_;
    const float bx  = (sigmoidf_(b0) + (float)x) * invW;
    const float by  = (sigmoidf_(b1) + (float)y) * invW;
    const float bw  = __expf(b2) * (aw3[a] * invW);
    const float bh  = __expf(b3) * (ah3[a] * invW);
    const float det = sigmoidf_(b4);      // both halves compute identically

    // softmax across 80 classes, split 40/40 over the lane pair
    float m = v[0];
#pragma unroll
    for (int c = 1; c < 40; ++c) m = fmaxf(m, v[c]);
    m = fmaxf(m, __shfl_xor(m, 32));
    float s = 0.0f;
#pragma unroll
    for (int c = 0; c < 40; ++c) { v[c] = __expf(v[c] - m); s += v[c]; }
    s += __shfl_xor(s, 32);
    const float scale = det / s;

    // ---- outputs ----
    // boxes: [B][A*HW][4] at offset 0; row index == P by construction
    if (half == 0) {
        ((float4*)out)[P] = make_float4(bx, by, bw, bh);
    }
    // confs: [B][A*HW][NC] after all boxes
    float* conf = out + (size_t)NPOS * 4 + (size_t)P * NC_ + half * 40;
#pragma unroll
    for (int c = 0; c < 40; c += 4) {
        *(float4*)(conf + c) = make_float4(v[c]     * scale,
                                           v[c + 1] * scale,
                                           v[c + 2] * scale,
                                           v[c + 3] * scale);
    }
}

extern "C" void kernel_launch(void* const* d_in, const int* in_sizes, int n_in,
                              void* d_out, int out_size, void* d_ws, size_t ws_size,
                              hipStream_t stream) {
    const float* in = (const float*)d_in[0];
    float* out = (float*)d_out;
    // 2 threads per position, 128 positions per 256-thread block
    const int nblocks = NPOS / 128;   // 2166, exact
    yolo_kernel<<<nblocks, 256, 0, stream>>>(in, out);
}

// Round 3
// 167.575 us; speedup vs baseline: 1.1498x; 1.1022x over previous
//
#include <hip/hip_runtime.h>

#define HW_   5776   // 76*76
#define W_    76
#define NC_   80     // classes
#define NA_   3      // anchors
#define NB_   16     // batch
#define NPOS  (NB_ * NA_ * HW_)   // 277248 total positions
#define ROWQ  24     // float4 slots per LDS row (96 floats: 80 real + pad for xor swizzle)

__device__ __forceinline__ float sigmoidf_(float x) {
    return 1.0f / (1.0f + __expf(-x));
}

// Two lanes per position compute (as R2); conf output staged through a
// per-wave LDS transpose so global stores are fully coalesced (the wave
// writes one contiguous 10 KB span instead of 64-line scattered stores).
// Per-wave buffer + in-order DS pipe => no __syncthreads needed.
__global__ __launch_bounds__(256) void yolo_kernel(const float* __restrict__ in,
                                                   float* __restrict__ out) {
    __shared__ float4 lds[4][32 * ROWQ];   // 12 KB per wave, 48 KB per block

    const int tid   = threadIdx.x;
    const int lane  = tid & 63;
    const int wv    = tid >> 6;           // wave within block (0..3)
    const int half  = lane >> 5;          // 0 or 1
    const int pos   = lane & 31;          // wave-local position index
    const int Pbase = blockIdx.x * 128 + wv * 32;  // first position of this wave
    const int P     = Pbase + pos;

    const int slab = P / HW_;             // = b*3 + a   (0..47)
    const int p    = P - slab * HW_;      // position in 76x76 plane
    const int a    = slab % NA_;

    const float aw3[3] = {1.5f, 2.375f, 5.0f};   // [12,19,40]/8
    const float ah3[3] = {2.0f, 4.5f, 3.5f};     // [16,36,28]/8
    const float invW = 1.0f / 76.0f;

    const float* src = in + (size_t)slab * (85 * (size_t)HW_) + p;

    // box channels 0..4 (same addresses across halves -> coalescer-merged)
    const float b0 = src[0 * (size_t)HW_];
    const float b1 = src[1 * (size_t)HW_];
    const float b2 = src[2 * (size_t)HW_];
    const float b3 = src[3 * (size_t)HW_];
    const float b4 = src[4 * (size_t)HW_];

    // this half's 40 class channels (each load: 2x contiguous 128B segments)
    const float* csrc = src + (size_t)(5 + half * 40) * HW_;
    float v[40];
#pragma unroll
    for (int c = 0; c < 40; ++c) v[c] = csrc[(size_t)c * HW_];

    const int x = p % W_;
    const int y = p / W_;
    const float bx  = (sigmoidf_(b0) + (float)x) * invW;
    const float by  = (sigmoidf_(b1) + (float)y) * invW;
    const float bw  = __expf(b2) * (aw3[a] * invW);
    const float bh  = __expf(b3) * (ah3[a] * invW);
    const float det = sigmoidf_(b4);

    // softmax across 80 classes, split 40/40 over the lane pair
    float m = v[0];
#pragma unroll
    for (int c = 1; c < 40; ++c) m = fmaxf(m, v[c]);
    m = fmaxf(m, __shfl_xor(m, 32));
    float s = 0.0f;
#pragma unroll
    for (int c = 0; c < 40; ++c) { v[c] = __expf(v[c] - m); s += v[c]; }
    s += __shfl_xor(s, 32);
    const float scale = det / s;

    // boxes: [B][A*HW][4]; row index == P; coalesced 512B per wave
    if (half == 0) {
        ((float4*)out)[P] = make_float4(bx, by, bw, bh);
    }

    // ---- stage conf into LDS (xor-swizzled float4 slots) ----
    // real quad index k = half*10 + i  (0..19); slot = pos*ROWQ + (k ^ (pos&7))
#pragma unroll
    for (int i = 0; i < 10; ++i) {
        const int k = half * 10 + i;
        const int slot = pos * ROWQ + (k ^ (pos & 7));
        lds[wv][slot] = make_float4(v[4 * i]     * scale,
                                    v[4 * i + 1] * scale,
                                    v[4 * i + 2] * scale,
                                    v[4 * i + 3] * scale);
    }

    // ---- drain LDS -> global, fully coalesced ----
    // wave covers flat float4 range [Pbase*20, Pbase*20 + 640)
    float4* conf4 = (float4*)out + NPOS + (size_t)Pbase * 20;
#pragma unroll
    for (int i = 0; i < 10; ++i) {
        const int f     = i * 64 + lane;      // 0..639
        const int pos_r = f / 20;
        const int k_r   = f - pos_r * 20;
        const int slot  = pos_r * ROWQ + (k_r ^ (pos_r & 7));
        conf4[f] = lds[wv][slot];
    }
}

extern "C" void kernel_launch(void* const* d_in, const int* in_sizes, int n_in,
                              void* d_out, int out_size, void* d_ws, size_t ws_size,
                              hipStream_t stream) {
    const float* in = (const float*)d_in[0];
    float* out = (float*)d_out;
    const int nblocks = NPOS / 128;   // 2166, exact
    yolo_kernel<<<nblocks, 256, 0, stream>>>(in, out);
}